// Round 11
// baseline (493.476 us; speedup 1.0000x reference)
//
#include <hip/hip_runtime.h>

// Sggnn_23218593202512 — round 24: single-barrier phases. R23 state: h/t
// at 675 TF, ~1900 cyc/phase vs ~620 cyc of MFMA need; loads have ~5000
// cyc slack (not latency/BW-bound) -> residual overhead is the 2
// barriers/phase. Restructure PHASE to {reads -> vmcnt -> barrier ->
// lgkm-drain -> stage -> MFMA}: the stage moves AFTER the barrier, which
// makes the second (WAR-guard) barrier redundant — a region read in phase
// P drains at P's post-bar lgkm, and its restage occurs post-bar(P'>=P+1)
// which happens-after every wave's P-drain. Same-phase / adjacent-phase
// stage targets verified disjoint from read regions (s1/s2=buf1.A vs
// buf0 reads; s3/s4=buf0.B vs buf0.A; s5/s6=buf0.A vs buf1; s7/s8=buf1.B
// vs buf1.A). vmcnt tightened: pre-bar at ph4/ph8 with vmcnt(2)
// (outstanding = one stage-slot of 2 loads). Barrier is asm w/ memory
// clobber: pins reads pre-bar (R22 lesson) and stages post-bar. MFMA
// order unchanged -> bit-identical. Everything else byte-identical R23.

typedef __bf16 bf16;
typedef __attribute__((ext_vector_type(8))) __bf16 bf16x8;
typedef __attribute__((ext_vector_type(4))) float f32x4;

#define EPSV 1e-5f

__device__ __forceinline__ void async_load16(const bf16* g, bf16* l) {
    __builtin_amdgcn_global_load_lds(
        (const __attribute__((address_space(1))) void*)g,
        (__attribute__((address_space(3))) void*)l, 16, 0, 0);
}

// 5 BN folds in one launch. Segments: [0,1024)=bn, [1024,2048)=rf1,
// [2048,3072)=rf2, [3072,3584)=sbn, [3584,4096)=fbn.
struct P5 { const float *g, *b, *m, *v, *bias; float *sc, *of; };
struct P5All { P5 p[5]; };
__global__ __launch_bounds__(256) void prep5_kernel(P5All a)
{
    int i = blockIdx.x * 256 + threadIdx.x;
    int seg, off;
    if      (i < 1024) { seg = 0; off = i; }
    else if (i < 2048) { seg = 1; off = i - 1024; }
    else if (i < 3072) { seg = 2; off = i - 2048; }
    else if (i < 3584) { seg = 3; off = i - 3072; }
    else               { seg = 4; off = i - 3584; }
    const P5& q = a.p[seg];
    float s = q.g[off] / sqrtf(q.v[off] + EPSV);
    float o = q.b[off] - q.m[off] * s;
    if (q.bias) o += q.bias[off] * s;
    q.sc[off] = s;
    q.of[off] = o;
}

// LDS-tiled transpose, 4 jobs in one launch (grid.z = job).
// out[n*K+k] = bf16(in[k*N+n]); 64x64 f32 tile, +1 pad, both sides
// coalesced. Jobs with N=512 idle half their y-blocks (early return).
struct TJob { const float* in; bf16* out; int K, N; };
struct TJobs { TJob j[4]; };
__global__ __launch_bounds__(256) void wtrans4_kernel(TJobs a)
{
    const TJob& jb = a.j[blockIdx.z];
    const int k0 = blockIdx.x * 64, n0 = blockIdx.y * 64;
    if (n0 >= jb.N || k0 >= jb.K) return;
    __shared__ float tile[64][65];
    const int c = threadIdx.x & 63, r4 = threadIdx.x >> 6;
#pragma unroll
    for (int i = 0; i < 16; ++i) {
        int r = r4 * 16 + i;
        tile[r][c] = jb.in[(size_t)(k0 + r) * jb.N + n0 + c];
    }
    __syncthreads();
#pragma unroll
    for (int i = 0; i < 16; ++i) {
        int r = r4 * 16 + i;
        jb.out[(size_t)(n0 + r) * jb.K + k0 + c] = (bf16)tile[c][r];
    }
}

// wT[g2*256+g1] = bf16(w[g1][g2] + scl_b); only g-tiles ta<=tb computed,
// mirror otherwise (w symmetric). [R11/R12-verified]
__global__ __launch_bounds__(256) void wconv_kernel(
    const float* __restrict__ w_acc, const float* __restrict__ sclb,
    bf16* __restrict__ wT)
{
    int tid = blockIdx.x * 256 + threadIdx.x;
    int g2 = tid >> 8, g1 = tid & 255;
    int idx = ((g1 >> 4) <= (g2 >> 4)) ? (g1 * 256 + g2) : (g2 * 256 + g1);
    wT[tid] = (bf16)(w_acc[idx] + sclb[0]);
}

// d[r][k] = bf16((f_p[gr>>8][k] - f_g[gr&255][k])^2 * ps[k] + po[k]),
// gr = rowOff + r. One bf16x8 per thread; writes coalesced 16B.
__global__ __launch_bounds__(256) void dprep_kernel(
    const float* __restrict__ X, const float* __restrict__ Y,
    const float* __restrict__ ps, const float* __restrict__ po,
    bf16* __restrict__ d, int rowOff)
{
    int t  = blockIdx.x * 256 + threadIdx.x;
    int k0 = (t & 127) * 8;           // 128 threads span one 1024-wide row
    int r  = t >> 7;
    int gr = rowOff + r;
    const float* xp = X + (size_t)(gr >> 8) * 1024 + k0;
    const float* yp = Y + (size_t)(gr & 255) * 1024 + k0;
    f32x4 x0 = *(const f32x4*)xp, x1 = *(const f32x4*)(xp + 4);
    f32x4 y0 = *(const f32x4*)yp, y1 = *(const f32x4*)(yp + 4);
    f32x4 sa = *(const f32x4*)(ps + k0), sb = *(const f32x4*)(ps + k0 + 4);
    f32x4 oa = *(const f32x4*)(po + k0), ob = *(const f32x4*)(po + k0 + 4);
    bf16x8 dv;
#pragma unroll
    for (int j = 0; j < 4; ++j) {
        float d0 = x0[j] - y0[j];
        float d1 = x1[j] - y1[j];
        dv[j]     = (bf16)(d0 * d0 * sa[j] + oa[j]);
        dv[j + 4] = (bf16)(d1 * d1 * sb[j] + ob[j]);
    }
    *(bf16x8*)&d[(size_t)r * 1024 + k0] = dv;
}

// dg for canonical gallery tile-pairs. Local row r of this chunk maps to
// pair-tile p = tileOff + (r>>8) -> triangular (ta,tb); rr = r&255:
// g1 = ta*16 + (rr>>4), g2 = tb*16 + (rr&15). Writes dg[r][k] bf16 and
// affmap[r] = g1*256+g2.
__global__ __launch_bounds__(256) void dgprep_kernel(
    const float* __restrict__ X,
    const float* __restrict__ ps, const float* __restrict__ po,
    bf16* __restrict__ dg, int* __restrict__ affmap, int tileOff)
{
    int t  = blockIdx.x * 256 + threadIdx.x;
    int k0 = (t & 127) * 8;
    int r  = t >> 7;
    int p  = tileOff + (r >> 8);
    int ta = 0, rem = p;
    while (rem >= 16 - ta) { rem -= 16 - ta; ++ta; }
    int tb = ta + rem;
    int rr = r & 255;
    int g1 = ta * 16 + (rr >> 4), g2 = tb * 16 + (rr & 15);
    const float* xp = X + (size_t)g1 * 1024 + k0;
    const float* yp = X + (size_t)g2 * 1024 + k0;
    f32x4 x0 = *(const f32x4*)xp, x1 = *(const f32x4*)(xp + 4);
    f32x4 y0 = *(const f32x4*)yp, y1 = *(const f32x4*)(yp + 4);
    f32x4 sa = *(const f32x4*)(ps + k0), sb = *(const f32x4*)(ps + k0 + 4);
    f32x4 oa = *(const f32x4*)(po + k0), ob = *(const f32x4*)(po + k0 + 4);
    bf16x8 dv;
#pragma unroll
    for (int j = 0; j < 4; ++j) {
        float d0 = x0[j] - y0[j];
        float d1 = x1[j] - y1[j];
        dv[j]     = (bf16)(d0 * d0 * sa[j] + oa[j]);
        dv[j + 4] = (bf16)(d1 * d1 * sb[j] + ob[j]);
    }
    *(bf16x8*)&dg[(size_t)r * 1024 + k0] = dv;
    if (k0 == 0) affmap[r] = g1 * 256 + g2;
}

// ---------- gemm128aff (R21-verified): affinity gemm, 2 blocks/CU --------
__global__ __launch_bounds__(256) void gemm128aff(
    const bf16* __restrict__ A,       // dgc [rows][K]
    const bf16* __restrict__ BT,      // sfcT [512][K]
    int K,
    const float* __restrict__ scale, const float* __restrict__ offset,
    const float* __restrict__ sclW, float* __restrict__ w_acc,
    const int* __restrict__ affmap)
{
    __shared__ bf16 As[2 * 128 * 64];   // 32 KiB
    __shared__ bf16 Bs[2 * 128 * 64];   // 32 KiB
    const int tid  = threadIdx.x;
    const int lane = tid & 63;
    const int wave = tid >> 6;
    const int wrow = wave >> 1, wcol = wave & 1;
    const int q = lane >> 4, l16 = lane & 15;

    int bx = blockIdx.x, by = blockIdx.y;
    {
        int nwg = gridDim.x * gridDim.y;
        if ((nwg & 7) == 0) {
            int lin = by * gridDim.x + bx;
            int cpx = nwg >> 3;
            int s = (lin & 7) * cpx + (lin >> 3);
            bx = s % gridDim.x;
            by = s / gridDim.x;
        }
    }
    const int row0 = by * 128;
    const int col0 = bx * 128;

    f32x4 acc[4][4];
#pragma unroll
    for (int mi = 0; mi < 4; ++mi)
#pragma unroll
        for (int ni = 0; ni < 4; ++ni)
#pragma unroll
            for (int e = 0; e < 4; ++e) acc[mi][ni][e] = 0.f;

    auto stageA = [&](int kk, bf16* dst) {
#pragma unroll
        for (int t = 0; t < 4; ++t) {
            int idx = t * 256 + tid;            // 1024 chunks (128 rows x 8)
            int r = idx >> 3, sch = idx & 7;
            int gch = sch ^ (r & 7);
            async_load16(A + (size_t)(row0 + r) * K + kk + gch * 8,
                         &dst[idx * 8]);
        }
    };
    auto stageB = [&](int kk, bf16* dst) {
#pragma unroll
        for (int t = 0; t < 4; ++t) {
            int idx = t * 256 + tid;
            int r = idx >> 3, sch = idx & 7;
            int gch = sch ^ (r & 7);
            async_load16(BT + (size_t)(col0 + r) * K + kk + gch * 8,
                         &dst[idx * 8]);
        }
    };

    stageA(0, As);
    stageB(0, Bs);

    int cur = 0;
    const int nt = K >> 6;
    for (int t = 0; t < nt; ++t) {
        const bool pf = (t + 1) < nt;
        if (pf) {
            stageA((t + 1) * 64, As + (cur ^ 1) * 8192);
            stageB((t + 1) * 64, Bs + (cur ^ 1) * 8192);
        }
        if (pf) {
            asm volatile("s_waitcnt vmcnt(8)\n\ts_barrier" ::: "memory");
        } else {
            asm volatile("s_waitcnt vmcnt(0) lgkmcnt(0)\n\ts_barrier"
                         ::: "memory");
        }
        const bf16* Asb = As + cur * 8192;
        const bf16* Bsb = Bs + cur * 8192;
#pragma unroll
        for (int s = 0; s < 2; ++s) {
            bf16x8 af[4], bfr[4];
#pragma unroll
            for (int mi = 0; mi < 4; ++mi) {
                int r = wrow * 64 + mi * 16 + l16;
                af[mi] = *(const bf16x8*)&Asb[r * 64 + (((s * 4 + q) ^ (r & 7)) * 8)];
            }
#pragma unroll
            for (int ni = 0; ni < 4; ++ni) {
                int rc = wcol * 64 + ni * 16 + l16;
                bfr[ni] = *(const bf16x8*)&Bsb[rc * 64 + (((s * 4 + q) ^ (rc & 7)) * 8)];
            }
#pragma unroll
            for (int mi = 0; mi < 4; ++mi)
#pragma unroll
                for (int ni = 0; ni < 4; ++ni)
                    acc[mi][ni] = __builtin_amdgcn_mfma_f32_16x16x32_bf16(
                        af[mi], bfr[ni], acc[mi][ni], 0, 0, 0);
        }
        if (pf) asm volatile("s_barrier" ::: "memory");
        cur ^= 1;
    }

#pragma unroll
    for (int mi = 0; mi < 4; ++mi)
#pragma unroll
        for (int i = 0; i < 4; ++i) {
            float rs = 0.f;
#pragma unroll
            for (int ni = 0; ni < 4; ++ni) {
                int cc = col0 + wcol * 64 + ni * 16 + l16;
                float val = acc[mi][ni][i] * scale[cc] + offset[cc];
                val = val > 0.f ? val : 0.1f * val;
                rs += val * sclW[cc];
            }
            rs += __shfl_xor(rs, 1, 64);
            rs += __shfl_xor(rs, 2, 64);
            rs += __shfl_xor(rs, 4, 64);
            rs += __shfl_xor(rs, 8, 64);
            if (l16 == 0) {
                int r = row0 + wrow * 64 + mi * 16 + q * 4 + i;
                atomicAdd(w_acc + affmap[r], rs);
            }
        }
}

// One phase (R24 single-barrier): {ds_read A-quad Q (+ all B if READB) ;
// VM (counted vmcnt, pre-bar) ; s_barrier (asm, memory clobber: pins reads
// pre-bar and stage post-bar) ; lgkmcnt(0) drain ; STAGE (post-bar!) ;
// setprio(1) 16 MFMA setprio(0)}. WAR proof in header comment.
#define PHASE(ASB, BSB, Q, READB, STAGE_STMT, VM_STMT)                        \
  {                                                                           \
    if (READB) {                                                              \
      _Pragma("unroll") for (int ni = 0; ni < 4; ++ni) {                      \
        int rc = wcol * 64 + ni * 16 + l16;                                   \
        bfr[ni][0] = *(const bf16x8*)&(BSB)[rc * 64 + (((q) ^ (rc & 7)) * 8)];\
        bfr[ni][1] = *(const bf16x8*)&(BSB)[rc * 64 + (((4 + q) ^ (rc & 7)) * 8)];\
      }                                                                       \
    }                                                                         \
    bf16x8 afq[2][2];                                                         \
    _Pragma("unroll") for (int m2 = 0; m2 < 2; ++m2) {                        \
      int r = wrow * 128 + ((Q) * 2 + m2) * 16 + l16;                         \
      afq[m2][0] = *(const bf16x8*)&(ASB)[r * 64 + (((q) ^ (r & 7)) * 8)];    \
      afq[m2][1] = *(const bf16x8*)&(ASB)[r * 64 + (((4 + q) ^ (r & 7)) * 8)];\
    }                                                                         \
    VM_STMT;                                                                  \
    asm volatile("s_barrier" ::: "memory");                                   \
    asm volatile("s_waitcnt lgkmcnt(0)" ::: "memory");                        \
    STAGE_STMT;                                                               \
    __builtin_amdgcn_s_setprio(1);                                            \
    _Pragma("unroll") for (int s = 0; s < 2; ++s)                             \
      _Pragma("unroll") for (int m2 = 0; m2 < 2; ++m2)                        \
        _Pragma("unroll") for (int ni = 0; ni < 4; ++ni)                      \
          acc[(Q) * 2 + m2][ni] = __builtin_amdgcn_mfma_f32_16x16x32_bf16(    \
              afq[m2][s], bfr[ni][s], acc[(Q) * 2 + m2][ni], 0, 0, 0);        \
    __builtin_amdgcn_s_setprio(0);                                            \
  }

// ---------- gemm256 (R24: single-barrier 8-phase; direct-d_out epi) -------
// C_z[M,N] = epi(A_z[M,K] @ BT_z[N,K]^T). 256x256 block, 512 thr = 8 waves
// (2 row x 4 col), wave 128x64 (acc[8][4]), BK=64, XOR-swizzled LDS,
// buf0 <-> even K-tiles, buf1 <-> odd K-tiles (64 KiB each).
// Stage slots (all post-bar): s1/s2 ph1/2 = buf1.A(T+1); s3/s4 ph3/4 =
// buf0.B(T+2); s5/s6 ph5/6 = buf0.A(T+2); s7/s8 ph7/8 = buf1.B(T+3).
// vmcnt(2) pre-bar at ph4 (outstanding = s3 only -> s1,s2,prev-s7,s8
// landed for ph5's buf1 reads) and ph8 (outstanding = s7 -> s3..s6 landed
// for next ph1's buf0 reads). Last iter: vmcnt(0) at ph4.
__global__ __launch_bounds__(512) void gemm256(
    const bf16* __restrict__ A,
    const bf16* __restrict__ BT,
    bf16* __restrict__ C,
    int K, int N,
    long long batchA, long long batchB, long long batchC,
    const float* __restrict__ scale, const float* __restrict__ offset,
    int lrelu,
    const float* __restrict__ fuseW, float* __restrict__ facc,
    long long faccStride,
    const int* __restrict__ affmap,
    const float* __restrict__ clsb)
{
    __shared__ bf16 As[2 * 256 * 64];   // 64 KiB (buf0|buf1)
    __shared__ bf16 Bs[2 * 256 * 64];   // 64 KiB (buf0|buf1)
    const int tid  = threadIdx.x;
    const int lane = tid & 63;
    const int wave = tid >> 6;
    const int wrow = wave >> 2, wcol = wave & 3;
    const int q = lane >> 4, l16 = lane & 15;
    const int z = blockIdx.z;

    // XCD-aware bijective swizzle (x fastest in dispatch order).
    int bx = blockIdx.x, by = blockIdx.y;
    {
        int nwg = gridDim.x * gridDim.y;
        if (gridDim.z == 1 && (nwg & 7) == 0) {
            int lin = by * gridDim.x + bx;
            int cpx = nwg >> 3;
            int s = (lin & 7) * cpx + (lin >> 3);
            bx = s % gridDim.x;
            by = s / gridDim.x;
        }
    }
    const int row0 = by * 256;
    const int col0 = bx * 256;

    const bf16* Ap = A + (size_t)z * (size_t)batchA;
    const bf16* Bp = BT + (size_t)z * (size_t)batchB;

    f32x4 acc[8][4];
#pragma unroll
    for (int mi = 0; mi < 8; ++mi)
#pragma unroll
        for (int ni = 0; ni < 4; ++ni)
#pragma unroll
            for (int e = 0; e < 4; ++e) acc[mi][ni][e] = 0.f;

    // stage one half-tile (rows h*128..h*128+127) = 2 async loads/thread
    auto stageA2 = [&](int kk, int buf, int h) {
#pragma unroll
        for (int tt = 0; tt < 2; ++tt) {
            int idx = (2 * h + tt) * 512 + tid;
            int r = idx >> 3, sch = idx & 7;
            int gch = sch ^ (r & 7);
            async_load16(Ap + (size_t)(row0 + r) * K + kk + gch * 8,
                         &As[buf * 16384 + idx * 8]);
        }
    };
    auto stageB2 = [&](int kk, int buf, int h) {
#pragma unroll
        for (int tt = 0; tt < 2; ++tt) {
            int idx = (2 * h + tt) * 512 + tid;
            int r = idx >> 3, sch = idx & 7;
            int gch = sch ^ (r & 7);
            async_load16(Bp + (size_t)(col0 + r) * K + kk + gch * 8,
                         &Bs[buf * 16384 + idx * 8]);
        }
    };

    // prologue: tile0 (A+B) -> buf0, tile1 B -> buf1  (6 halves, 12 loads)
    stageA2(0, 0, 0); stageA2(0, 0, 1);
    stageB2(0, 0, 0); stageB2(0, 0, 1);
    stageB2(64, 1, 0); stageB2(64, 1, 1);
    // wait buf0's 8 loads (oldest); buf1.B's 4 stay in flight
    asm volatile("s_waitcnt vmcnt(4)\n\ts_barrier" ::: "memory");

    bf16x8 bfr[4][2];
    const bf16* A0 = As;          const bf16* B0 = Bs;
    const bf16* A1 = As + 16384;  const bf16* B1 = Bs + 16384;
    const int nt = K >> 6;        // even for all call sites (16 or 4)
    for (int i2 = 0; i2 < nt; i2 += 2) {
        const int kk1 = (i2 + 1) << 6, kk2 = (i2 + 2) << 6,
                  kk3 = (i2 + 3) << 6;
        const bool more = (i2 + 2) < nt;   // tiles i2+2 AND i2+3 exist
        // ---- tile i2 from buf0 (phases 1-4) ----
        PHASE(A0, B0, 0, true,  { stageA2(kk1, 1, 0); }, {});
        PHASE(A0, B0, 1, false, { stageA2(kk1, 1, 1); }, {});
        PHASE(A0, B0, 2, false, { if (more) stageB2(kk2, 0, 0); }, {});
        PHASE(A0, B0, 3, false, { if (more) stageB2(kk2, 0, 1); },
              { if (more)
                    asm volatile("s_waitcnt vmcnt(2)" ::: "memory");
                else
                    asm volatile("s_waitcnt vmcnt(0)" ::: "memory"); });
        // ---- tile i2+1 from buf1 (phases 5-8) ----
        PHASE(A1, B1, 0, true,  { if (more) stageA2(kk2, 0, 0); }, {});
        PHASE(A1, B1, 1, false, { if (more) stageA2(kk2, 0, 1); }, {});
        PHASE(A1, B1, 2, false, { if (more) stageB2(kk3, 1, 0); }, {});
        PHASE(A1, B1, 3, false, { if (more) stageB2(kk3, 1, 1); },
              { if (more)
                    asm volatile("s_waitcnt vmcnt(2)" ::: "memory"); });
    }

    // C/D layout (m89-verified): col = lane&15, row = (lane>>4)*4 + reg
    if (fuseW) {
        const float cb = (clsb && col0 == 0 && wcol == 0) ? clsb[0] : 0.f;
#pragma unroll
        for (int mi = 0; mi < 8; ++mi)
#pragma unroll
            for (int i = 0; i < 4; ++i) {
                float rs = 0.f;
#pragma unroll
                for (int ni = 0; ni < 4; ++ni) {
                    int cc = col0 + wcol * 64 + ni * 16 + l16;
                    float val = acc[mi][ni][i] * scale[cc] + offset[cc];
                    val = val > 0.f ? val : 0.1f * val;
                    rs += val * fuseW[cc];
                }
                rs += __shfl_xor(rs, 1, 64);
                rs += __shfl_xor(rs, 2, 64);
                rs += __shfl_xor(rs, 4, 64);
                rs += __shfl_xor(rs, 8, 64);
                if (l16 == 0) {
                    int r = row0 + wrow * 128 + mi * 16 + q * 4 + i;
                    float* dst = affmap ? (facc + affmap[r])
                                        : (facc + (size_t)z * faccStride + r);
                    atomicAdd(dst, rs + cb);
                }
            }
        return;
    }
    bf16* Cp = C + (size_t)z * (size_t)batchC;
#pragma unroll
    for (int mi = 0; mi < 8; ++mi)
#pragma unroll
        for (int ni = 0; ni < 4; ++ni)
#pragma unroll
            for (int i = 0; i < 4; ++i) {
                int r = row0 + wrow * 128 + mi * 16 + q * 4 + i;
                int cc = col0 + wcol * 64 + ni * 16 + l16;
                float val = acc[mi][ni][i];
                if (scale) val = val * scale[cc] + offset[cc];
                if (lrelu) val = val > 0.f ? val : 0.1f * val;
                Cp[(size_t)r * N + cc] = (bf16)val;
            }
}

extern "C" void kernel_launch(void* const* d_in, const int* in_sizes, int n_in,
                              void* d_out, int out_size, void* d_ws, size_t ws_size,
                              hipStream_t stream)
{
    const float* f_p   = (const float*)d_in[0];
    const float* f_g   = (const float*)d_in[1];
    const float* bn_g  = (const float*)d_in[2];
    const float* bn_b  = (const float*)d_in[3];
    const float* bn_m  = (const float*)d_in[4];
    const float* bn_v  = (const float*)d_in[5];
    const float* rf_W1 = (const float*)d_in[6];
    const float* rf_b1 = (const float*)d_in[7];
    const float* rf1_g = (const float*)d_in[8];
    const float* rf1_b = (const float*)d_in[9];
    const float* rf1_m = (const float*)d_in[10];
    const float* rf1_v = (const float*)d_in[11];
    const float* rf_W2 = (const float*)d_in[12];
    const float* rf_b2 = (const float*)d_in[13];
    const float* rf2_g = (const float*)d_in[14];
    const float* rf2_b = (const float*)d_in[15];
    const float* rf2_m = (const float*)d_in[16];
    const float* rf2_v = (const float*)d_in[17];
    const float* sfc_W = (const float*)d_in[18];
    const float* sfc_b = (const float*)d_in[19];
    const float* sbn_g = (const float*)d_in[20];
    const float* sbn_b = (const float*)d_in[21];
    const float* sbn_m = (const float*)d_in[22];
    const float* sbn_v = (const float*)d_in[23];
    const float* scl_W = (const float*)d_in[24];
    const float* scl_b = (const float*)d_in[25];
    const float* ffc_W = (const float*)d_in[26];
    const float* ffc_b = (const float*)d_in[27];
    const float* fbn_g = (const float*)d_in[28];
    const float* fbn_b = (const float*)d_in[29];
    const float* fbn_m = (const float*)d_in[30];
    const float* fbn_v = (const float*)d_in[31];
    const float* cls_W = (const float*)d_in[32];
    const float* cls_b = (const float*)d_in[33];

    const size_t MB = 1ull << 20;
    char* ws = (char*)d_ws;
    float* SC      = (float*)(ws);
    float *s0 = SC,        *o0 = SC + 1024;
    float *s1 = SC + 2048, *o1 = SC + 3072;
    float *s2 = SC + 4096, *o2 = SC + 5120;
    float *s3 = SC + 6144, *o3 = SC + 6656;
    float *s4 = SC + 7168, *o4 = SC + 7680;
    float* w_acc   = (float*)(ws + 65536);       // 256 KiB
    bf16* wT       = (bf16*)(ws + 458752);       // 128 KiB
    int*  affmap   = (int*)(ws + 589824);        // 139 KiB (34816 ints)
    bf16* W1T      = (bf16*)(ws + 1 * MB);
    bf16* W2T      = (bf16*)(ws + 3 * MB);
    bf16* sfcT     = (bf16*)(ws + 5 * MB);
    bf16* ffcT     = (bf16*)(ws + 6 * MB);

    int nc;
    if      (ws_size >= 170 * MB) nc = 1;        // confirmed since R3
    else if (ws_size >= 90 * MB)  nc = 2;
    else                          nc = 4;
    const int pc = 128 / nc;
    const int R  = pc * 256;
    const size_t hbytes = (size_t)R * 1024 * 2;
    bf16* bufA = (bf16*)(ws + 8 * MB);                    // h
    bf16* bufB = (bf16*)(ws + 8 * MB + hbytes);           // d, then t
    bf16* bufC = (bf16*)(ws + 8 * MB + 2 * hbytes);       // uT [pc][512][256]

    // 1. BN folds (one fused launch)
    {
        P5All a;
        a.p[0] = { bn_g,  bn_b,  bn_m,  bn_v,  nullptr, s0, o0 };
        a.p[1] = { rf1_g, rf1_b, rf1_m, rf1_v, rf_b1,   s1, o1 };
        a.p[2] = { rf2_g, rf2_b, rf2_m, rf2_v, rf_b2,   s2, o2 };
        a.p[3] = { sbn_g, sbn_b, sbn_m, sbn_v, sfc_b,   s3, o3 };
        a.p[4] = { fbn_g, fbn_b, fbn_m, fbn_v, ffc_b,   s4, o4 };
        prep5_kernel<<<dim3(16), 256, 0, stream>>>(a);
    }

    // 2. weight transposes (f32 -> bf16), one launch for all 4
    {
        TJobs tj;
        tj.j[0] = { rf_W1, W1T, 1024, 1024 };
        tj.j[1] = { rf_W2, W2T, 1024, 1024 };
        tj.j[2] = { sfc_W, sfcT, 1024, 512 };
        tj.j[3] = { ffc_W, ffcT, 1024, 512 };
        wtrans4_kernel<<<dim3(16, 16, 4), 256, 0, stream>>>(tj);
    }

    // 3. zero accumulators: w_acc, and d_out (feat atomics land there)
    hipMemsetAsync(ws + 65536, 0, 262144, stream);
    hipMemsetAsync(d_out, 0, 131072, stream);

    // 4. symmetric affinity: dgprep materializes dgc, then the 2-blocks/CU
    //    128^2 gemm -> atomicAdd w_acc[affmap[r]]. [R21-verified]
    {
        bf16* dgc = (bf16*)(ws + 8 * MB);    // up to 71.3 MB (na=1)
        const int na = (ws_size >= 170 * MB) ? 1 : 2;
        const int TP = 136 / na;             // pair-tiles per chunk
        for (int ai = 0; ai < na; ++ai) {
            const int rows = TP * 256;
            dgprep_kernel<<<dim3(rows / 2), 256, 0, stream>>>(
                f_g, s0, o0, dgc, affmap + ai * TP * 256, ai * TP);
            gemm128aff<<<dim3(4, rows / 128), 256, 0, stream>>>(
                dgc, sfcT, 1024, s3, o3, scl_W, w_acc,
                affmap + ai * TP * 256);
        }
    }
    // 5. wT[g2][g1] = bf16(w[canon] + scl_b)
    wconv_kernel<<<dim3(256), 256, 0, stream>>>(w_acc, scl_b, wT);

    // 6. probe chunks (all gemms single-barrier 8-phase; d into bufB)
    for (int ci = 0; ci < nc; ++ci) {
        // d = bn1((f_p - f_g)^2)        [R,1024] bf16 -> bufB (dead after h)
        dprep_kernel<<<dim3(R / 2), 256, 0, stream>>>(
            f_p, f_g, s0, o0, bufB, ci * R);
        // h = lrelu(rf1(d @ W1 + b1))   [R,1024]
        gemm256<<<dim3(4, R / 256), 512, 0, stream>>>(
            bufB, W1T, bufA, 1024, 1024,
            0, 0, 0, s1, o1, 1, nullptr, nullptr, 0, nullptr, nullptr);
        // t = lrelu(rf2(h @ W2 + b2))   [R,1024] (overwrites d: dead)
        gemm256<<<dim3(4, R / 256), 512, 0, stream>>>(
            bufA, W2T, bufB, 1024, 1024,
            0, 0, 0, s2, o2, 1, nullptr, nullptr, 0, nullptr, nullptr);
        // uT_p = ffcT @ t_p^T           [pc][512][256]  (batched)
        gemm256<<<dim3(1, 2, pc), 512, 0, stream>>>(
            ffcT, bufB, bufC, 1024, 256,
            0, (long long)256 * 1024, (long long)512 * 256,
            nullptr, nullptr, 0, nullptr, nullptr, 0, nullptr, nullptr);
        // feat_p = lrelu(fbn(wT @ uT_p^T + b)) . cls_W (+cls_b once)
        //   -> atomicAdd directly into d_out
        gemm256<<<dim3(2, 1, pc), 512, 0, stream>>>(
            wT, bufC, nullptr, 256, 512,
            0, (long long)512 * 256, 0,
            s4, o4, 1, cls_W, (float*)d_out + (size_t)ci * pc * 256, 256,
            nullptr, cls_b);
    }
}

// Round 12
// 475.341 us; speedup vs baseline: 1.0382x; 1.0382x over previous
//
#include <hip/hip_runtime.h>

// Sggnn_23218593202512 — round 25: dispatch consolidation. R24's
// single-barrier test was null (102.4us h/t, MfmaUtil 26.6 == R23) ->
// phase-schedule levers exhausted; core at 675 TF = documented plain-HIP
// plateau band for this structure at K=1024 (m248v2: 735). Remaining
// addressable time: launch gaps + tiny dispatches (12 graph nodes).
// Consolidate to 8: (1) setup_kernel = 4x wtrans + prep5 + zero w_acc +
// zero d_out in ONE launch (grid (16,16,5): z<4 transpose jobs, z==4
// by-split: by0=prep5, by1=zero w_acc, by2=zero d_out); (2)
// wconv_dprep_kernel fuses wconv (256 tail blocks) + dprep (16384
// blocks) — wconv reads w_acc (complete), dprep's bufB write clobbers
// only the dead dgc tail (identical aliasing to the sequential order).
// nc==1 fast path; nc>1 keeps the R24-verified sequence. gemm256 /
// gemm128aff / dgprep byte-identical to R24.

typedef __bf16 bf16;
typedef __attribute__((ext_vector_type(8))) __bf16 bf16x8;
typedef __attribute__((ext_vector_type(4))) float f32x4;

#define EPSV 1e-5f

__device__ __forceinline__ void async_load16(const bf16* g, bf16* l) {
    __builtin_amdgcn_global_load_lds(
        (const __attribute__((address_space(1))) void*)g,
        (__attribute__((address_space(3))) void*)l, 16, 0, 0);
}

struct P5 { const float *g, *b, *m, *v, *bias; float *sc, *of; };
struct TJob { const float* in; bf16* out; int K, N; };
struct SetupArgs { TJob j[4]; P5 p[5]; float* wacc; float* dout; };

// One launch: z<4 = LDS-tiled transpose job z (out[n*K+k]=bf16(in[k*N+n]),
// 64x64 f32 tile, +1 pad, both sides coalesced); z==4: by0 = 5 BN folds
// (segments [0,1024)bn [1024,2048)rf1 [2048,3072)rf2 [3072,3584)sbn
// [3584,4096)fbn), by1 = zero w_acc (65536 f32), by2 = zero d_out (32768).
__global__ __launch_bounds__(256) void setup_kernel(SetupArgs a)
{
    if (blockIdx.z < 4) {
        const TJob& jb = a.j[blockIdx.z];
        const int k0 = blockIdx.x * 64, n0 = blockIdx.y * 64;
        if (n0 >= jb.N || k0 >= jb.K) return;
        __shared__ float tile[64][65];
        const int c = threadIdx.x & 63, r4 = threadIdx.x >> 6;
#pragma unroll
        for (int i = 0; i < 16; ++i) {
            int r = r4 * 16 + i;
            tile[r][c] = jb.in[(size_t)(k0 + r) * jb.N + n0 + c];
        }
        __syncthreads();
#pragma unroll
        for (int i = 0; i < 16; ++i) {
            int r = r4 * 16 + i;
            jb.out[(size_t)(n0 + r) * jb.K + k0 + c] = (bf16)tile[c][r];
        }
        return;
    }
    const int bx = blockIdx.x, by = blockIdx.y;
    if (by == 0) {                       // prep5 (16 blocks x 256 = 4096)
        int i = bx * 256 + threadIdx.x;
        int seg, off;
        if      (i < 1024) { seg = 0; off = i; }
        else if (i < 2048) { seg = 1; off = i - 1024; }
        else if (i < 3072) { seg = 2; off = i - 2048; }
        else if (i < 3584) { seg = 3; off = i - 3072; }
        else               { seg = 4; off = i - 3584; }
        const P5& q = a.p[seg];
        float s = q.g[off] / sqrtf(q.v[off] + EPSV);
        float o = q.b[off] - q.m[off] * s;
        if (q.bias) o += q.bias[off] * s;
        q.sc[off] = s;
        q.of[off] = o;
    } else if (by == 1) {                // zero w_acc: 16 blk x 256 x 16
        float* p = a.wacc + (size_t)(bx * 256 + threadIdx.x) * 16;
        f32x4 z = {0.f, 0.f, 0.f, 0.f};
        *(f32x4*)(p) = z; *(f32x4*)(p + 4) = z;
        *(f32x4*)(p + 8) = z; *(f32x4*)(p + 12) = z;
    } else if (by == 2) {                // zero d_out: 16 blk x 256 x 8
        float* p = a.dout + (size_t)(bx * 256 + threadIdx.x) * 8;
        f32x4 z = {0.f, 0.f, 0.f, 0.f};
        *(f32x4*)(p) = z; *(f32x4*)(p + 4) = z;
    }
}

// wT[g2*256+g1] = bf16(w[g1][g2] + scl_b); canonical-mirror (w symmetric).
__device__ __forceinline__ void wconv_body(
    const float* w_acc, const float* sclb, bf16* wT, int tid)
{
    int g2 = tid >> 8, g1 = tid & 255;
    int idx = ((g1 >> 4) <= (g2 >> 4)) ? (g1 * 256 + g2) : (g2 * 256 + g1);
    wT[tid] = (bf16)(w_acc[idx] + sclb[0]);
}

__global__ __launch_bounds__(256) void wconv_kernel(
    const float* __restrict__ w_acc, const float* __restrict__ sclb,
    bf16* __restrict__ wT)
{
    wconv_body(w_acc, sclb, wT, blockIdx.x * 256 + threadIdx.x);
}

// d[r][k] = bf16((X[gr>>8][k] - Y[gr&255][k])^2 * ps[k] + po[k]).
__device__ __forceinline__ void dprep_body(
    const float* X, const float* Y, const float* ps, const float* po,
    bf16* d, int rowOff, int blk, int tix)
{
    int t  = blk * 256 + tix;
    int k0 = (t & 127) * 8;
    int r  = t >> 7;
    int gr = rowOff + r;
    const float* xp = X + (size_t)(gr >> 8) * 1024 + k0;
    const float* yp = Y + (size_t)(gr & 255) * 1024 + k0;
    f32x4 x0 = *(const f32x4*)xp, x1 = *(const f32x4*)(xp + 4);
    f32x4 y0 = *(const f32x4*)yp, y1 = *(const f32x4*)(yp + 4);
    f32x4 sa = *(const f32x4*)(ps + k0), sb = *(const f32x4*)(ps + k0 + 4);
    f32x4 oa = *(const f32x4*)(po + k0), ob = *(const f32x4*)(po + k0 + 4);
    bf16x8 dv;
#pragma unroll
    for (int j = 0; j < 4; ++j) {
        float d0 = x0[j] - y0[j];
        float d1 = x1[j] - y1[j];
        dv[j]     = (bf16)(d0 * d0 * sa[j] + oa[j]);
        dv[j + 4] = (bf16)(d1 * d1 * sb[j] + ob[j]);
    }
    *(bf16x8*)&d[(size_t)r * 1024 + k0] = dv;
}

__global__ __launch_bounds__(256) void dprep_kernel(
    const float* __restrict__ X, const float* __restrict__ Y,
    const float* __restrict__ ps, const float* __restrict__ po,
    bf16* __restrict__ d, int rowOff)
{
    dprep_body(X, Y, ps, po, d, rowOff, blockIdx.x, threadIdx.x);
}

// Fused: blocks [0,ndblk) = dprep; blocks [ndblk, ndblk+256) = wconv.
__global__ __launch_bounds__(256) void wconv_dprep_kernel(
    const float* __restrict__ w_acc, const float* __restrict__ sclb,
    bf16* __restrict__ wT,
    const float* __restrict__ X, const float* __restrict__ Y,
    const float* __restrict__ ps, const float* __restrict__ po,
    bf16* __restrict__ d, int rowOff, int ndblk)
{
    if ((int)blockIdx.x >= ndblk) {
        wconv_body(w_acc, sclb, wT,
                   ((int)blockIdx.x - ndblk) * 256 + threadIdx.x);
        return;
    }
    dprep_body(X, Y, ps, po, d, rowOff, blockIdx.x, threadIdx.x);
}

// dg for canonical gallery tile-pairs (triangular map); writes dg[r][k]
// bf16 and affmap[r] = g1*256+g2. [R19-verified]
__global__ __launch_bounds__(256) void dgprep_kernel(
    const float* __restrict__ X,
    const float* __restrict__ ps, const float* __restrict__ po,
    bf16* __restrict__ dg, int* __restrict__ affmap, int tileOff)
{
    int t  = blockIdx.x * 256 + threadIdx.x;
    int k0 = (t & 127) * 8;
    int r  = t >> 7;
    int p  = tileOff + (r >> 8);
    int ta = 0, rem = p;
    while (rem >= 16 - ta) { rem -= 16 - ta; ++ta; }
    int tb = ta + rem;
    int rr = r & 255;
    int g1 = ta * 16 + (rr >> 4), g2 = tb * 16 + (rr & 15);
    const float* xp = X + (size_t)g1 * 1024 + k0;
    const float* yp = X + (size_t)g2 * 1024 + k0;
    f32x4 x0 = *(const f32x4*)xp, x1 = *(const f32x4*)(xp + 4);
    f32x4 y0 = *(const f32x4*)yp, y1 = *(const f32x4*)(yp + 4);
    f32x4 sa = *(const f32x4*)(ps + k0), sb = *(const f32x4*)(ps + k0 + 4);
    f32x4 oa = *(const f32x4*)(po + k0), ob = *(const f32x4*)(po + k0 + 4);
    bf16x8 dv;
#pragma unroll
    for (int j = 0; j < 4; ++j) {
        float d0 = x0[j] - y0[j];
        float d1 = x1[j] - y1[j];
        dv[j]     = (bf16)(d0 * d0 * sa[j] + oa[j]);
        dv[j + 4] = (bf16)(d1 * d1 * sb[j] + ob[j]);
    }
    *(bf16x8*)&dg[(size_t)r * 1024 + k0] = dv;
    if (k0 == 0) affmap[r] = g1 * 256 + g2;
}

// ---------- gemm128aff (R21-verified): affinity gemm, 2 blocks/CU --------
__global__ __launch_bounds__(256) void gemm128aff(
    const bf16* __restrict__ A,       // dgc [rows][K]
    const bf16* __restrict__ BT,      // sfcT [512][K]
    int K,
    const float* __restrict__ scale, const float* __restrict__ offset,
    const float* __restrict__ sclW, float* __restrict__ w_acc,
    const int* __restrict__ affmap)
{
    __shared__ bf16 As[2 * 128 * 64];   // 32 KiB
    __shared__ bf16 Bs[2 * 128 * 64];   // 32 KiB
    const int tid  = threadIdx.x;
    const int lane = tid & 63;
    const int wave = tid >> 6;
    const int wrow = wave >> 1, wcol = wave & 1;
    const int q = lane >> 4, l16 = lane & 15;

    int bx = blockIdx.x, by = blockIdx.y;
    {
        int nwg = gridDim.x * gridDim.y;
        if ((nwg & 7) == 0) {
            int lin = by * gridDim.x + bx;
            int cpx = nwg >> 3;
            int s = (lin & 7) * cpx + (lin >> 3);
            bx = s % gridDim.x;
            by = s / gridDim.x;
        }
    }
    const int row0 = by * 128;
    const int col0 = bx * 128;

    f32x4 acc[4][4];
#pragma unroll
    for (int mi = 0; mi < 4; ++mi)
#pragma unroll
        for (int ni = 0; ni < 4; ++ni)
#pragma unroll
            for (int e = 0; e < 4; ++e) acc[mi][ni][e] = 0.f;

    auto stageA = [&](int kk, bf16* dst) {
#pragma unroll
        for (int t = 0; t < 4; ++t) {
            int idx = t * 256 + tid;            // 1024 chunks (128 rows x 8)
            int r = idx >> 3, sch = idx & 7;
            int gch = sch ^ (r & 7);
            async_load16(A + (size_t)(row0 + r) * K + kk + gch * 8,
                         &dst[idx * 8]);
        }
    };
    auto stageB = [&](int kk, bf16* dst) {
#pragma unroll
        for (int t = 0; t < 4; ++t) {
            int idx = t * 256 + tid;
            int r = idx >> 3, sch = idx & 7;
            int gch = sch ^ (r & 7);
            async_load16(BT + (size_t)(col0 + r) * K + kk + gch * 8,
                         &dst[idx * 8]);
        }
    };

    stageA(0, As);
    stageB(0, Bs);

    int cur = 0;
    const int nt = K >> 6;
    for (int t = 0; t < nt; ++t) {
        const bool pf = (t + 1) < nt;
        if (pf) {
            stageA((t + 1) * 64, As + (cur ^ 1) * 8192);
            stageB((t + 1) * 64, Bs + (cur ^ 1) * 8192);
        }
        if (pf) {
            asm volatile("s_waitcnt vmcnt(8)\n\ts_barrier" ::: "memory");
        } else {
            asm volatile("s_waitcnt vmcnt(0) lgkmcnt(0)\n\ts_barrier"
                         ::: "memory");
        }
        const bf16* Asb = As + cur * 8192;
        const bf16* Bsb = Bs + cur * 8192;
#pragma unroll
        for (int s = 0; s < 2; ++s) {
            bf16x8 af[4], bfr[4];
#pragma unroll
            for (int mi = 0; mi < 4; ++mi) {
                int r = wrow * 64 + mi * 16 + l16;
                af[mi] = *(const bf16x8*)&Asb[r * 64 + (((s * 4 + q) ^ (r & 7)) * 8)];
            }
#pragma unroll
            for (int ni = 0; ni < 4; ++ni) {
                int rc = wcol * 64 + ni * 16 + l16;
                bfr[ni] = *(const bf16x8*)&Bsb[rc * 64 + (((s * 4 + q) ^ (rc & 7)) * 8)];
            }
#pragma unroll
            for (int mi = 0; mi < 4; ++mi)
#pragma unroll
                for (int ni = 0; ni < 4; ++ni)
                    acc[mi][ni] = __builtin_amdgcn_mfma_f32_16x16x32_bf16(
                        af[mi], bfr[ni], acc[mi][ni], 0, 0, 0);
        }
        if (pf) asm volatile("s_barrier" ::: "memory");
        cur ^= 1;
    }

#pragma unroll
    for (int mi = 0; mi < 4; ++mi)
#pragma unroll
        for (int i = 0; i < 4; ++i) {
            float rs = 0.f;
#pragma unroll
            for (int ni = 0; ni < 4; ++ni) {
                int cc = col0 + wcol * 64 + ni * 16 + l16;
                float val = acc[mi][ni][i] * scale[cc] + offset[cc];
                val = val > 0.f ? val : 0.1f * val;
                rs += val * sclW[cc];
            }
            rs += __shfl_xor(rs, 1, 64);
            rs += __shfl_xor(rs, 2, 64);
            rs += __shfl_xor(rs, 4, 64);
            rs += __shfl_xor(rs, 8, 64);
            if (l16 == 0) {
                int r = row0 + wrow * 64 + mi * 16 + q * 4 + i;
                atomicAdd(w_acc + affmap[r], rs);
            }
        }
}

// One phase: {ds_read A-quad Q (+ all B if READB) ; VM ; s_barrier ;
// lgkmcnt(0) (memory clobber pins reads pre-bar — R22 lesson) ; STAGE
// (post-bar) ; setprio(1) 16 MFMA setprio(0)}. [R24-verified]
#define PHASE(ASB, BSB, Q, READB, STAGE_STMT, VM_STMT)                        \
  {                                                                           \
    if (READB) {                                                              \
      _Pragma("unroll") for (int ni = 0; ni < 4; ++ni) {                      \
        int rc = wcol * 64 + ni * 16 + l16;                                   \
        bfr[ni][0] = *(const bf16x8*)&(BSB)[rc * 64 + (((q) ^ (rc & 7)) * 8)];\
        bfr[ni][1] = *(const bf16x8*)&(BSB)[rc * 64 + (((4 + q) ^ (rc & 7)) * 8)];\
      }                                                                       \
    }                                                                         \
    bf16x8 afq[2][2];                                                         \
    _Pragma("unroll") for (int m2 = 0; m2 < 2; ++m2) {                        \
      int r = wrow * 128 + ((Q) * 2 + m2) * 16 + l16;                         \
      afq[m2][0] = *(const bf16x8*)&(ASB)[r * 64 + (((q) ^ (r & 7)) * 8)];    \
      afq[m2][1] = *(const bf16x8*)&(ASB)[r * 64 + (((4 + q) ^ (r & 7)) * 8)];\
    }                                                                         \
    VM_STMT;                                                                  \
    asm volatile("s_barrier" ::: "memory");                                   \
    asm volatile("s_waitcnt lgkmcnt(0)" ::: "memory");                        \
    STAGE_STMT;                                                               \
    __builtin_amdgcn_s_setprio(1);                                            \
    _Pragma("unroll") for (int s = 0; s < 2; ++s)                             \
      _Pragma("unroll") for (int m2 = 0; m2 < 2; ++m2)                        \
        _Pragma("unroll") for (int ni = 0; ni < 4; ++ni)                      \
          acc[(Q) * 2 + m2][ni] = __builtin_amdgcn_mfma_f32_16x16x32_bf16(    \
              afq[m2][s], bfr[ni][s], acc[(Q) * 2 + m2][ni], 0, 0, 0);        \
    __builtin_amdgcn_s_setprio(0);                                            \
  }

// ---------- gemm256 (R24-verified single-barrier 8-phase) -----------------
__global__ __launch_bounds__(512) void gemm256(
    const bf16* __restrict__ A,
    const bf16* __restrict__ BT,
    bf16* __restrict__ C,
    int K, int N,
    long long batchA, long long batchB, long long batchC,
    const float* __restrict__ scale, const float* __restrict__ offset,
    int lrelu,
    const float* __restrict__ fuseW, float* __restrict__ facc,
    long long faccStride,
    const int* __restrict__ affmap,
    const float* __restrict__ clsb)
{
    __shared__ bf16 As[2 * 256 * 64];   // 64 KiB (buf0|buf1)
    __shared__ bf16 Bs[2 * 256 * 64];   // 64 KiB (buf0|buf1)
    const int tid  = threadIdx.x;
    const int lane = tid & 63;
    const int wave = tid >> 6;
    const int wrow = wave >> 2, wcol = wave & 3;
    const int q = lane >> 4, l16 = lane & 15;
    const int z = blockIdx.z;

    // XCD-aware bijective swizzle (x fastest in dispatch order).
    int bx = blockIdx.x, by = blockIdx.y;
    {
        int nwg = gridDim.x * gridDim.y;
        if (gridDim.z == 1 && (nwg & 7) == 0) {
            int lin = by * gridDim.x + bx;
            int cpx = nwg >> 3;
            int s = (lin & 7) * cpx + (lin >> 3);
            bx = s % gridDim.x;
            by = s / gridDim.x;
        }
    }
    const int row0 = by * 256;
    const int col0 = bx * 256;

    const bf16* Ap = A + (size_t)z * (size_t)batchA;
    const bf16* Bp = BT + (size_t)z * (size_t)batchB;

    f32x4 acc[8][4];
#pragma unroll
    for (int mi = 0; mi < 8; ++mi)
#pragma unroll
        for (int ni = 0; ni < 4; ++ni)
#pragma unroll
            for (int e = 0; e < 4; ++e) acc[mi][ni][e] = 0.f;

    // stage one half-tile (rows h*128..h*128+127) = 2 async loads/thread
    auto stageA2 = [&](int kk, int buf, int h) {
#pragma unroll
        for (int tt = 0; tt < 2; ++tt) {
            int idx = (2 * h + tt) * 512 + tid;
            int r = idx >> 3, sch = idx & 7;
            int gch = sch ^ (r & 7);
            async_load16(Ap + (size_t)(row0 + r) * K + kk + gch * 8,
                         &As[buf * 16384 + idx * 8]);
        }
    };
    auto stageB2 = [&](int kk, int buf, int h) {
#pragma unroll
        for (int tt = 0; tt < 2; ++tt) {
            int idx = (2 * h + tt) * 512 + tid;
            int r = idx >> 3, sch = idx & 7;
            int gch = sch ^ (r & 7);
            async_load16(Bp + (size_t)(col0 + r) * K + kk + gch * 8,
                         &Bs[buf * 16384 + idx * 8]);
        }
    };

    // prologue: tile0 (A+B) -> buf0, tile1 B -> buf1  (6 halves, 12 loads)
    stageA2(0, 0, 0); stageA2(0, 0, 1);
    stageB2(0, 0, 0); stageB2(0, 0, 1);
    stageB2(64, 1, 0); stageB2(64, 1, 1);
    // wait buf0's 8 loads (oldest); buf1.B's 4 stay in flight
    asm volatile("s_waitcnt vmcnt(4)\n\ts_barrier" ::: "memory");

    bf16x8 bfr[4][2];
    const bf16* A0 = As;          const bf16* B0 = Bs;
    const bf16* A1 = As + 16384;  const bf16* B1 = Bs + 16384;
    const int nt = K >> 6;        // even for all call sites (16 or 4)
    for (int i2 = 0; i2 < nt; i2 += 2) {
        const int kk1 = (i2 + 1) << 6, kk2 = (i2 + 2) << 6,
                  kk3 = (i2 + 3) << 6;
        const bool more = (i2 + 2) < nt;   // tiles i2+2 AND i2+3 exist
        // ---- tile i2 from buf0 (phases 1-4) ----
        PHASE(A0, B0, 0, true,  { stageA2(kk1, 1, 0); }, {});
        PHASE(A0, B0, 1, false, { stageA2(kk1, 1, 1); }, {});
        PHASE(A0, B0, 2, false, { if (more) stageB2(kk2, 0, 0); }, {});
        PHASE(A0, B0, 3, false, { if (more) stageB2(kk2, 0, 1); },
              { if (more)
                    asm volatile("s_waitcnt vmcnt(2)" ::: "memory");
                else
                    asm volatile("s_waitcnt vmcnt(0)" ::: "memory"); });
        // ---- tile i2+1 from buf1 (phases 5-8) ----
        PHASE(A1, B1, 0, true,  { if (more) stageA2(kk2, 0, 0); }, {});
        PHASE(A1, B1, 1, false, { if (more) stageA2(kk2, 0, 1); }, {});
        PHASE(A1, B1, 2, false, { if (more) stageB2(kk3, 1, 0); }, {});
        PHASE(A1, B1, 3, false, { if (more) stageB2(kk3, 1, 1); },
              { if (more)
                    asm volatile("s_waitcnt vmcnt(2)" ::: "memory"); });
    }

    // C/D layout (m89-verified): col = lane&15, row = (lane>>4)*4 + reg
    if (fuseW) {
        const float cb = (clsb && col0 == 0 && wcol == 0) ? clsb[0] : 0.f;
#pragma unroll
        for (int mi = 0; mi < 8; ++mi)
#pragma unroll
            for (int i = 0; i < 4; ++i) {
                float rs = 0.f;
#pragma unroll
                for (int ni = 0; ni < 4; ++ni) {
                    int cc = col0 + wcol * 64 + ni * 16 + l16;
                    float val = acc[mi][ni][i] * scale[cc] + offset[cc];
                    val = val > 0.f ? val : 0.1f * val;
                    rs += val * fuseW[cc];
                }
                rs += __shfl_xor(rs, 1, 64);
                rs += __shfl_xor(rs, 2, 64);
                rs += __shfl_xor(rs, 4, 64);
                rs += __shfl_xor(rs, 8, 64);
                if (l16 == 0) {
                    int r = row0 + wrow * 128 + mi * 16 + q * 4 + i;
                    float* dst = affmap ? (facc + affmap[r])
                                        : (facc + (size_t)z * faccStride + r);
                    atomicAdd(dst, rs + cb);
                }
            }
        return;
    }
    bf16* Cp = C + (size_t)z * (size_t)batchC;
#pragma unroll
    for (int mi = 0; mi < 8; ++mi)
#pragma unroll
        for (int ni = 0; ni < 4; ++ni)
#pragma unroll
            for (int i = 0; i < 4; ++i) {
                int r = row0 + wrow * 128 + mi * 16 + q * 4 + i;
                int cc = col0 + wcol * 64 + ni * 16 + l16;
                float val = acc[mi][ni][i];
                if (scale) val = val * scale[cc] + offset[cc];
                if (lrelu) val = val > 0.f ? val : 0.1f * val;
                Cp[(size_t)r * N + cc] = (bf16)val;
            }
}

extern "C" void kernel_launch(void* const* d_in, const int* in_sizes, int n_in,
                              void* d_out, int out_size, void* d_ws, size_t ws_size,
                              hipStream_t stream)
{
    const float* f_p   = (const float*)d_in[0];
    const float* f_g   = (const float*)d_in[1];
    const float* bn_g  = (const float*)d_in[2];
    const float* bn_b  = (const float*)d_in[3];
    const float* bn_m  = (const float*)d_in[4];
    const float* bn_v  = (const float*)d_in[5];
    const float* rf_W1 = (const float*)d_in[6];
    const float* rf_b1 = (const float*)d_in[7];
    const float* rf1_g = (const float*)d_in[8];
    const float* rf1_b = (const float*)d_in[9];
    const float* rf1_m = (const float*)d_in[10];
    const float* rf1_v = (const float*)d_in[11];
    const float* rf_W2 = (const float*)d_in[12];
    const float* rf_b2 = (const float*)d_in[13];
    const float* rf2_g = (const float*)d_in[14];
    const float* rf2_b = (const float*)d_in[15];
    const float* rf2_m = (const float*)d_in[16];
    const float* rf2_v = (const float*)d_in[17];
    const float* sfc_W = (const float*)d_in[18];
    const float* sfc_b = (const float*)d_in[19];
    const float* sbn_g = (const float*)d_in[20];
    const float* sbn_b = (const float*)d_in[21];
    const float* sbn_m = (const float*)d_in[22];
    const float* sbn_v = (const float*)d_in[23];
    const float* scl_W = (const float*)d_in[24];
    const float* scl_b = (const float*)d_in[25];
    const float* ffc_W = (const float*)d_in[26];
    const float* ffc_b = (const float*)d_in[27];
    const float* fbn_g = (const float*)d_in[28];
    const float* fbn_b = (const float*)d_in[29];
    const float* fbn_m = (const float*)d_in[30];
    const float* fbn_v = (const float*)d_in[31];
    const float* cls_W = (const float*)d_in[32];
    const float* cls_b = (const float*)d_in[33];

    const size_t MB = 1ull << 20;
    char* ws = (char*)d_ws;
    float* SC      = (float*)(ws);
    float *s0 = SC,        *o0 = SC + 1024;
    float *s1 = SC + 2048, *o1 = SC + 3072;
    float *s2 = SC + 4096, *o2 = SC + 5120;
    float *s3 = SC + 6144, *o3 = SC + 6656;
    float *s4 = SC + 7168, *o4 = SC + 7680;
    float* w_acc   = (float*)(ws + 65536);       // 256 KiB
    bf16* wT       = (bf16*)(ws + 458752);       // 128 KiB
    int*  affmap   = (int*)(ws + 589824);        // 139 KiB (34816 ints)
    bf16* W1T      = (bf16*)(ws + 1 * MB);
    bf16* W2T      = (bf16*)(ws + 3 * MB);
    bf16* sfcT     = (bf16*)(ws + 5 * MB);
    bf16* ffcT     = (bf16*)(ws + 6 * MB);

    int nc;
    if      (ws_size >= 170 * MB) nc = 1;        // confirmed since R3
    else if (ws_size >= 90 * MB)  nc = 2;
    else                          nc = 4;
    const int pc = 128 / nc;
    const int R  = pc * 256;
    const size_t hbytes = (size_t)R * 1024 * 2;
    bf16* bufA = (bf16*)(ws + 8 * MB);                    // h
    bf16* bufB = (bf16*)(ws + 8 * MB + hbytes);           // d, then t
    bf16* bufC = (bf16*)(ws + 8 * MB + 2 * hbytes);       // uT [pc][512][256]

    // 1. setup: 4 weight transposes + 5 BN folds + zero w_acc + zero d_out
    {
        SetupArgs sa;
        sa.j[0] = { rf_W1, W1T, 1024, 1024 };
        sa.j[1] = { rf_W2, W2T, 1024, 1024 };
        sa.j[2] = { sfc_W, sfcT, 1024, 512 };
        sa.j[3] = { ffc_W, ffcT, 1024, 512 };
        sa.p[0] = { bn_g,  bn_b,  bn_m,  bn_v,  nullptr, s0, o0 };
        sa.p[1] = { rf1_g, rf1_b, rf1_m, rf1_v, rf_b1,   s1, o1 };
        sa.p[2] = { rf2_g, rf2_b, rf2_m, rf2_v, rf_b2,   s2, o2 };
        sa.p[3] = { sbn_g, sbn_b, sbn_m, sbn_v, sfc_b,   s3, o3 };
        sa.p[4] = { fbn_g, fbn_b, fbn_m, fbn_v, ffc_b,   s4, o4 };
        sa.wacc = w_acc;
        sa.dout = (float*)d_out;
        setup_kernel<<<dim3(16, 16, 5), 256, 0, stream>>>(sa);
    }

    // 2. symmetric affinity: dgprep materializes dgc, then the 2-blocks/CU
    //    128^2 gemm -> atomicAdd w_acc[affmap[r]]. [R21-verified]
    {
        bf16* dgc = (bf16*)(ws + 8 * MB);    // up to 68 MB (na=1)
        const int na = (nc == 1) ? 1 : 2;
        const int TP = 136 / na;             // pair-tiles per chunk
        for (int ai = 0; ai < na; ++ai) {
            const int rows = TP * 256;
            dgprep_kernel<<<dim3(rows / 2), 256, 0, stream>>>(
                f_g, s0, o0, dgc, affmap + ai * TP * 256, ai * TP);
            gemm128aff<<<dim3(4, rows / 128), 256, 0, stream>>>(
                dgc, sfcT, 1024, s3, o3, scl_W, w_acc,
                affmap + ai * TP * 256);
        }
    }

    if (nc == 1) {
        // 3. fused wconv + dprep (dprep's bufB write clobbers only the
        //    dead dgc tail — same aliasing as the sequential order)
        wconv_dprep_kernel<<<dim3(R / 2 + 256), 256, 0, stream>>>(
            w_acc, scl_b, wT, f_p, f_g, s0, o0, bufB, 0, R / 2);
        // 4. h = lrelu(rf1(d @ W1 + b1))   [R,1024]
        gemm256<<<dim3(4, R / 256), 512, 0, stream>>>(
            bufB, W1T, bufA, 1024, 1024,
            0, 0, 0, s1, o1, 1, nullptr, nullptr, 0, nullptr, nullptr);
        // 5. t = lrelu(rf2(h @ W2 + b2))   [R,1024]
        gemm256<<<dim3(4, R / 256), 512, 0, stream>>>(
            bufA, W2T, bufB, 1024, 1024,
            0, 0, 0, s2, o2, 1, nullptr, nullptr, 0, nullptr, nullptr);
        // 6. uT_p = ffcT @ t_p^T           [pc][512][256]  (batched)
        gemm256<<<dim3(1, 2, pc), 512, 0, stream>>>(
            ffcT, bufB, bufC, 1024, 256,
            0, (long long)256 * 1024, (long long)512 * 256,
            nullptr, nullptr, 0, nullptr, nullptr, 0, nullptr, nullptr);
        // 7. feat -> atomicAdd directly into d_out (+cls_b once)
        gemm256<<<dim3(2, 1, pc), 512, 0, stream>>>(
            wT, bufC, nullptr, 256, 512,
            0, (long long)512 * 256, 0,
            s4, o4, 1, cls_W, (float*)d_out, 256, nullptr, cls_b);
    } else {
        // fallback: R24-verified sequence
        wconv_kernel<<<dim3(256), 256, 0, stream>>>(w_acc, scl_b, wT);
        for (int ci = 0; ci < nc; ++ci) {
            dprep_kernel<<<dim3(R / 2), 256, 0, stream>>>(
                f_p, f_g, s0, o0, bufB, ci * R);
            gemm256<<<dim3(4, R / 256), 512, 0, stream>>>(
                bufB, W1T, bufA, 1024, 1024,
                0, 0, 0, s1, o1, 1, nullptr, nullptr, 0, nullptr, nullptr);
            gemm256<<<dim3(4, R / 256), 512, 0, stream>>>(
                bufA, W2T, bufB, 1024, 1024,
                0, 0, 0, s2, o2, 1, nullptr, nullptr, 0, nullptr, nullptr);
            gemm256<<<dim3(1, 2, pc), 512, 0, stream>>>(
                ffcT, bufB, bufC, 1024, 256,
                0, (long long)256 * 1024, (long long)512 * 256,
                nullptr, nullptr, 0, nullptr, nullptr, 0, nullptr, nullptr);
            gemm256<<<dim3(2, 1, pc), 512, 0, stream>>>(
                wT, bufC, nullptr, 256, 512,
                0, (long long)512 * 256, 0,
                s4, o4, 1, cls_W, (float*)d_out + (size_t)ci * pc * 256, 256,
                nullptr, cls_b);
        }
    }
}